// Round 8
// baseline (1288.850 us; speedup 1.0000x reference)
//
#include <hip/hip_runtime.h>
#include <hip/hip_fp16.h>

// Problem constants
#define IN_CAPS  1152
#define NUM_CAPS 10
#define DIM_CAPS 16
#define B_TOT    256

// single fused kernel: 512 blocks x 256 threads.
// Residency: __launch_bounds__(256,2) => VGPR<=256 => 2 waves/SIMD => 2 blocks/CU
// => capacity 512 == grid, all blocks co-resident (required by spin barrier).
#define I_T     9                  // i's per block -> 128 i-tiles
#define P_TILES (IN_CAPS / I_T)    // 128
#define B_BLK   64                 // batches per block: 4 waves x 16 (MFMA M=16)
#define NBLK    512
#define NTHR    256
#define S_ELEMS (B_TOT * NUM_CAPS * DIM_CAPS)   // 40960

// ws layout: bar[64] ints | Vbuf[40960] | spart[128*40960] | Wh[1152*10*64 uint4]
#define BAR_I   64
#define VBUF_F  S_ELEMS
#define SPART_F (P_TILES * S_ELEMS)

typedef _Float16 f16x8 __attribute__((ext_vector_type(8)));
typedef float    f32x4 __attribute__((ext_vector_type(4)));

// ---- 16-lane (d) sum reduction, pure VALU via DPP row ops (no LDS) ----
template <int CTRL>
__device__ __forceinline__ float dpp_add16(float v) {
  int p = __builtin_amdgcn_update_dpp(0, __float_as_int(v), CTRL, 0xF, 0xF, true);
  return v + __int_as_float(p);
}
__device__ __forceinline__ float red16(float v) {
  v = dpp_add16<0xB1>(v);   // quad_perm xor1
  v = dpp_add16<0x4E>(v);   // quad_perm xor2
  v = dpp_add16<0x141>(v);  // row_half_mirror
  v = dpp_add16<0x140>(v);  // row_mirror
  return v;                 // all 16 lanes hold the d-sum
}

__device__ __forceinline__ unsigned packh2(float a, float b) {
  __half2 h = __float22half2_rn(make_float2(a, b));
  return *reinterpret_cast<unsigned*>(&h);
}

// split x into f16 hi + f16 lo residual: one MFMA (k0-7=hi, k8-15=lo vs
// duplicated W) gives x*W at ~fp32 accuracy.
__device__ __forceinline__ void split2(float a, float b, unsigned& hi, unsigned& lo) {
  __half2 h = __float22half2_rn(make_float2(a, b));
  float2 f = __half22float2(h);
  __half2 l2 = __float22half2_rn(make_float2(a - f.x, b - f.y));
  hi = *reinterpret_cast<unsigned*>(&h);
  lo = *reinterpret_cast<unsigned*>(&l2);
}

// Grid-wide barrier from device-scope atomics (the grid.sync primitive).
// Bounded spin: if residency ever falls short we produce a WRONG answer and a
// failing bench with counters -- never a hung container.
__device__ __forceinline__ void gbar(int* bar, int k) {
  __threadfence();
  __syncthreads();
  if (threadIdx.x == 0) {
    atomicAdd(&bar[k], 1);
    long spin = 0;
    while (__hip_atomic_load(&bar[k], __ATOMIC_ACQUIRE,
                             __HIP_MEMORY_SCOPE_AGENT) < NBLK) {
      __builtin_amdgcn_s_sleep(2);
      if (++spin > (1L << 22)) break;   // safety escape
    }
  }
  __syncthreads();
  __threadfence();
}

// One kernel, whole op: W-pack -> 4 x { route -> gbar -> reduce+squash -> gbar }.
// Route core is the R6-proven LDS-staged MFMA loop; pass 0 runs with V=0
// registers (exp(0)=1, es=10 -> c=0.1 exactly, same math as ZERO_V).
__global__ __launch_bounds__(256, 2) void caps_kernel(
    const float* __restrict__ x, const float* __restrict__ W,
    int* __restrict__ bar, uint4* __restrict__ Wh, float* __restrict__ Vbuf,
    float* __restrict__ spart, float* __restrict__ out) {
  __shared__ uint4 sbuf[2][NUM_CAPS * 64];   // 2 x 10 KB

  const int tid  = threadIdx.x;
  const int bid  = blockIdx.x;
  const int gtid = bid * NTHR + tid;

  // ---- phase W: pack W[0][n][i][d][k8] -> Wh[i][n][lane] f16 B-fragments ----
  {
    const float4* Wf4 = (const float4*)W;
    for (int e = gtid; e < IN_CAPS * NUM_CAPS * 64; e += NBLK * NTHR) {
      const int i = e / (NUM_CAPS * 64);
      const int r = e - i * (NUM_CAPS * 64);
      const int n = r >> 6;
      const int l = r & 63;
      uint4 v = make_uint4(0u, 0u, 0u, 0u);
      if ((l >> 4) <= 1) {       // k-groups 0,1 both carry W[d][0..7]
        const int d = l & 15;
        float4 w0 = Wf4[((size_t)(n * IN_CAPS + i) * DIM_CAPS + d) * 2];
        float4 w1 = Wf4[((size_t)(n * IN_CAPS + i) * DIM_CAPS + d) * 2 + 1];
        v.x = packh2(w0.x, w0.y);  v.y = packh2(w0.z, w0.w);
        v.z = packh2(w1.x, w1.y);  v.w = packh2(w1.z, w1.w);
      }
      Wh[e] = v;
    }
  }
  gbar(bar, 0);

  // ---- block decode (stable across passes -> per-XCD L2 stays hot) ----
  const int l   = tid & 63;
  const int w   = tid >> 6;          // wave 0..3
  const int g   = l >> 4;            // k-group / C-row-group
  const int d   = l & 15;            // A-row selector AND C-col (=d)
  const int xcd = bid & 7;
  const int r_  = bid >> 3;          // 0..63
  const int tile = xcd * 16 + (r_ & 15);   // 0..127
  const int bblk = r_ >> 4;                // 0..3
  const int i0   = tile * I_T;
  const int wb   = bblk * B_BLK + w * 16;  // wave's 16-batch base
  const int bA   = wb + d;                 // batch this lane loads for A
  const int bC0  = wb + g * 4;             // C rows: bC0 + r, r=0..3

  const uint4* Whg = Wh + (size_t)i0 * (NUM_CAPS * 64);
  const float4* xp = (const float4*)x;
  const f32x4 zc = {0.f, 0.f, 0.f, 0.f};
  const uint4 z4 = make_uint4(0u, 0u, 0u, 0u);

  for (int p = 0; p < 4; ++p) {
    // V registers (zeros for pass 0 -> softmax yields c = 0.1 exactly)
    float V[NUM_CAPS][4];
    if (p > 0) {
#pragma unroll
      for (int n = 0; n < NUM_CAPS; ++n)
#pragma unroll
        for (int r = 0; r < 4; ++r)
          V[n][r] = Vbuf[((size_t)(bC0 + r) * NUM_CAPS + n) * DIM_CAPS + d];
    } else {
#pragma unroll
      for (int n = 0; n < NUM_CAPS; ++n)
#pragma unroll
        for (int r = 0; r < 4; ++r) V[n][r] = 0.f;
    }

    f32x4 s[NUM_CAPS];
#pragma unroll
    for (int n = 0; n < NUM_CAPS; ++n) s[n] = (f32x4){0.f, 0.f, 0.f, 0.f};

    // prologue: stage i0 into sbuf[0], prefetch x(i0)
    {
      uint4 r0 = Whg[tid];
      uint4 r1 = Whg[256 + tid];
      uint4 r2 = make_uint4(0u, 0u, 0u, 0u);
      if (tid < 128) r2 = Whg[512 + tid];
      sbuf[0][tid] = r0;
      sbuf[0][256 + tid] = r1;
      if (tid < 128) sbuf[0][512 + tid] = r2;
    }
    float4 xa = xp[(size_t)(bA * IN_CAPS + i0) * 2];
    float4 xb = xp[(size_t)(bA * IN_CAPS + i0) * 2 + 1];
    __syncthreads();

    for (int ii = 0; ii < I_T; ++ii) {
      const int cur   = ii & 1;
      const bool more = (ii + 1 < I_T);   // uniform
      uint4 p0, p1, p2;
      float4 xan, xbn;
      if (more) {   // issue next-i loads; consumed at bottom -> latency hidden
        const uint4* Whn = Whg + (size_t)(ii + 1) * (NUM_CAPS * 64);
        p0 = Whn[tid];
        p1 = Whn[256 + tid];
        if (tid < 128) p2 = Whn[512 + tid];
        xan = xp[(size_t)(bA * IN_CAPS + (i0 + ii + 1)) * 2];
        xbn = xp[(size_t)(bA * IN_CAPS + (i0 + ii + 1)) * 2 + 1];
      }

      // A-fragment: k0-7 = f16(x) hi, k8-15 = residual lo, k>=16 zero
      uint4 ah, al;
      split2(xa.x, xa.y, ah.x, al.x);
      split2(xa.z, xa.w, ah.y, al.y);
      split2(xb.x, xb.y, ah.z, al.z);
      split2(xb.z, xb.w, ah.w, al.w);
      uint4 as = (g == 0) ? ah : ((g == 1) ? al : z4);
      f16x8 af = __builtin_bit_cast(f16x8, as);

      const uint4* sb = sbuf[cur];
      f32x4 u[NUM_CAPS];
#pragma unroll
      for (int n = 0; n < NUM_CAPS; ++n) {
        f16x8 bf = __builtin_bit_cast(f16x8, sb[n * 64 + l]);   // ds_read_b128
        u[n] = __builtin_amdgcn_mfma_f32_16x16x32_f16(af, bf, zc, 0, 0, 0);
      }

      float e[NUM_CAPS][4];
      float es[4] = {0.f, 0.f, 0.f, 0.f};
#pragma unroll
      for (int n = 0; n < NUM_CAPS; ++n)
#pragma unroll
        for (int r = 0; r < 4; ++r) {
          e[n][r] = __expf(red16(u[n][r] * V[n][r]));
          es[r] += e[n][r];
        }
      float inv[4];
#pragma unroll
      for (int r = 0; r < 4; ++r) inv[r] = 1.f / es[r];
#pragma unroll
      for (int n = 0; n < NUM_CAPS; ++n)
#pragma unroll
        for (int r = 0; r < 4; ++r)
          s[n][r] += (e[n][r] * inv[r]) * u[n][r];

      if (more) {
        uint4* nb = sbuf[cur ^ 1];
        nb[tid] = p0;
        nb[256 + tid] = p1;
        if (tid < 128) nb[512 + tid] = p2;
        xa = xan; xb = xbn;
        __syncthreads();
      }
    }

    // spart[tile][b][n][d]; 16 d-lanes per row-group write 64B contiguous
#pragma unroll
    for (int n = 0; n < NUM_CAPS; ++n)
#pragma unroll
      for (int r = 0; r < 4; ++r)
        spart[((size_t)(tile * B_TOT + bC0 + r) * NUM_CAPS + n) * DIM_CAPS + d]
            = s[n][r];

    gbar(bar, 1 + 2 * p);

    // ---- reduce + squash phase (first 160 blocks carry the 40960 elems) ----
    if (gtid < S_ELEMS) {
      float sv = 0.f;
#pragma unroll 16
      for (int tl = 0; tl < P_TILES; ++tl)
        sv += spart[(size_t)tl * S_ELEMS + gtid];
      float sq = sv * sv;
#pragma unroll
      for (int m = 1; m < 16; m <<= 1) sq += __shfl_xor(sq, m, 16);  // sum over d
      float norm = sqrtf(sq);
      float vv = sv * (sq / (1.f + sq)) / (norm + 1e-8f);
      if (p == 3)      out[gtid]  = vv;
      else if (p == 0) Vbuf[gtid] = vv;
      else             Vbuf[gtid] += vv;
    }
    if (p < 3) gbar(bar, 2 + 2 * p);
  }
}

extern "C" void kernel_launch(void* const* d_in, const int* in_sizes, int n_in,
                              void* d_out, int out_size, void* d_ws, size_t ws_size,
                              hipStream_t stream) {
  const float* x = (const float*)d_in[0];  // [256,1152,8]
  const float* W = (const float*)d_in[1];  // [1,10,1152,16,8]
  float* out   = (float*)d_out;            // [256,10,16]
  int*   bar   = (int*)d_ws;
  float* Vbuf  = (float*)d_ws + BAR_I;
  float* spart = Vbuf + VBUF_F;
  uint4* Wh    = (uint4*)(spart + SPART_F);

  // barrier counters must start at 0 every launch (ws is poisoned between runs)
  (void)hipMemsetAsync(bar, 0, BAR_I * sizeof(int), stream);

  caps_kernel<<<NBLK, NTHR, 0, stream>>>(x, W, bar, Wh, Vbuf, spart, out);
}

// Round 9
// 544.550 us; speedup vs baseline: 2.3668x; 2.3668x over previous
//
#include <hip/hip_runtime.h>
#include <hip/hip_fp16.h>

// Problem constants
#define IN_CAPS  1152
#define NUM_CAPS 10
#define DIM_CAPS 16
#define B_TOT    256

// single fused kernel: 512 blocks x 256 threads.
// Residency: __launch_bounds__(256,2) => 2 blocks/CU => capacity 512 == grid.
// R8 PASSED -> co-residency + spin-barrier release are PROVEN; R8's 5x slowdown
// was the fence storm (per-thread threadfence + acquire-per-poll), fixed here.
#define I_T     9                  // i's per block -> 128 i-tiles
#define P_TILES (IN_CAPS / I_T)    // 128
#define B_BLK   64                 // batches per block: 4 waves x 16 (MFMA M=16)
#define NBLK    512
#define NTHR    256
#define S_ELEMS (B_TOT * NUM_CAPS * DIM_CAPS)   // 40960

// ws layout: bar[64] ints | Vbuf[40960] | spart[128*40960] | Wh[1152*10*64 uint4]
#define BAR_I   64
#define VBUF_F  S_ELEMS
#define SPART_F (P_TILES * S_ELEMS)

typedef _Float16 f16x8 __attribute__((ext_vector_type(8)));
typedef float    f32x4 __attribute__((ext_vector_type(4)));

// ---- 16-lane (d) sum reduction, pure VALU via DPP row ops (no LDS) ----
template <int CTRL>
__device__ __forceinline__ float dpp_add16(float v) {
  int p = __builtin_amdgcn_update_dpp(0, __float_as_int(v), CTRL, 0xF, 0xF, true);
  return v + __int_as_float(p);
}
__device__ __forceinline__ float red16(float v) {
  v = dpp_add16<0xB1>(v);   // quad_perm xor1
  v = dpp_add16<0x4E>(v);   // quad_perm xor2
  v = dpp_add16<0x141>(v);  // row_half_mirror
  v = dpp_add16<0x140>(v);  // row_mirror
  return v;                 // all 16 lanes hold the d-sum
}

__device__ __forceinline__ unsigned packh2(float a, float b) {
  __half2 h = __float22half2_rn(make_float2(a, b));
  return *reinterpret_cast<unsigned*>(&h);
}

// split x into f16 hi + f16 lo residual: one MFMA (k0-7=hi, k8-15=lo vs
// duplicated W) gives x*W at ~fp32 accuracy.
__device__ __forceinline__ void split2(float a, float b, unsigned& hi, unsigned& lo) {
  __half2 h = __float22half2_rn(make_float2(a, b));
  float2 f = __half22float2(h);
  __half2 l2 = __float22half2_rn(make_float2(a - f.x, b - f.y));
  hi = *reinterpret_cast<unsigned*>(&h);
  lo = *reinterpret_cast<unsigned*>(&l2);
}

// Grid barrier, fence-minimal protocol:
//   __syncthreads (drains block stores to L2)
//   thread0: RELEASE atomicAdd   -> ONE buffer_wbl2 per block
//            RELAXED polls       -> coherent-point reads, NO per-poll invalidate
//            ONE ACQUIRE load    -> ONE buffer_inv per block
//   __syncthreads
// Bounded spin: wrong answer + failing bench on residency error, never a hang.
__device__ __forceinline__ void gbar(int* bar, int k) {
  __syncthreads();
  if (threadIdx.x == 0) {
    __hip_atomic_fetch_add(&bar[k], 1, __ATOMIC_RELEASE,
                           __HIP_MEMORY_SCOPE_AGENT);
    long spin = 0;
    while (__hip_atomic_load(&bar[k], __ATOMIC_RELAXED,
                             __HIP_MEMORY_SCOPE_AGENT) < NBLK) {
      __builtin_amdgcn_s_sleep(8);
      if (++spin > (1L << 20)) break;   // safety escape
    }
    (void)__hip_atomic_load(&bar[k], __ATOMIC_ACQUIRE,
                            __HIP_MEMORY_SCOPE_AGENT);
  }
  __syncthreads();
}

// One kernel, whole op: W-pack -> 4 x { route -> gbar -> reduce+squash -> gbar }.
// Route core is the R6-proven LDS-staged MFMA loop; pass 0 runs with V=0
// registers (exp(0)=1, es=10 -> c=0.1 exactly, same math as ZERO_V).
__global__ __launch_bounds__(256, 2) void caps_kernel(
    const float* __restrict__ x, const float* __restrict__ W,
    int* __restrict__ bar, uint4* __restrict__ Wh, float* __restrict__ Vbuf,
    float* __restrict__ spart, float* __restrict__ out) {
  __shared__ uint4 sbuf[2][NUM_CAPS * 64];   // 2 x 10 KB

  const int tid  = threadIdx.x;
  const int bid  = blockIdx.x;
  const int gtid = bid * NTHR + tid;

  // ---- phase W: pack W[0][n][i][d][k8] -> Wh[i][n][lane] f16 B-fragments ----
  {
    const float4* Wf4 = (const float4*)W;
    for (int e = gtid; e < IN_CAPS * NUM_CAPS * 64; e += NBLK * NTHR) {
      const int i = e / (NUM_CAPS * 64);
      const int r = e - i * (NUM_CAPS * 64);
      const int n = r >> 6;
      const int l = r & 63;
      uint4 v = make_uint4(0u, 0u, 0u, 0u);
      if ((l >> 4) <= 1) {       // k-groups 0,1 both carry W[d][0..7]
        const int d = l & 15;
        float4 w0 = Wf4[((size_t)(n * IN_CAPS + i) * DIM_CAPS + d) * 2];
        float4 w1 = Wf4[((size_t)(n * IN_CAPS + i) * DIM_CAPS + d) * 2 + 1];
        v.x = packh2(w0.x, w0.y);  v.y = packh2(w0.z, w0.w);
        v.z = packh2(w1.x, w1.y);  v.w = packh2(w1.z, w1.w);
      }
      Wh[e] = v;
    }
  }
  gbar(bar, 0);

  // ---- block decode (stable across passes -> per-XCD L2 stays hot) ----
  const int l   = tid & 63;
  const int w   = tid >> 6;          // wave 0..3
  const int g   = l >> 4;            // k-group / C-row-group
  const int d   = l & 15;            // A-row selector AND C-col (=d)
  const int xcd = bid & 7;
  const int r_  = bid >> 3;          // 0..63
  const int tile = xcd * 16 + (r_ & 15);   // 0..127
  const int bblk = r_ >> 4;                // 0..3
  const int i0   = tile * I_T;
  const int wb   = bblk * B_BLK + w * 16;  // wave's 16-batch base
  const int bA   = wb + d;                 // batch this lane loads for A
  const int bC0  = wb + g * 4;             // C rows: bC0 + r, r=0..3

  const uint4* Whg = Wh + (size_t)i0 * (NUM_CAPS * 64);
  const float4* xp = (const float4*)x;
  const f32x4 zc = {0.f, 0.f, 0.f, 0.f};
  const uint4 z4 = make_uint4(0u, 0u, 0u, 0u);

  for (int p = 0; p < 4; ++p) {
    // V registers (zeros for pass 0 -> softmax yields c = 0.1 exactly)
    float V[NUM_CAPS][4];
    if (p > 0) {
#pragma unroll
      for (int n = 0; n < NUM_CAPS; ++n)
#pragma unroll
        for (int r = 0; r < 4; ++r)
          V[n][r] = Vbuf[((size_t)(bC0 + r) * NUM_CAPS + n) * DIM_CAPS + d];
    } else {
#pragma unroll
      for (int n = 0; n < NUM_CAPS; ++n)
#pragma unroll
        for (int r = 0; r < 4; ++r) V[n][r] = 0.f;
    }

    f32x4 s[NUM_CAPS];
#pragma unroll
    for (int n = 0; n < NUM_CAPS; ++n) s[n] = (f32x4){0.f, 0.f, 0.f, 0.f};

    // prologue: stage i0 into sbuf[0], prefetch x(i0)
    {
      uint4 r0 = Whg[tid];
      uint4 r1 = Whg[256 + tid];
      uint4 r2 = make_uint4(0u, 0u, 0u, 0u);
      if (tid < 128) r2 = Whg[512 + tid];
      sbuf[0][tid] = r0;
      sbuf[0][256 + tid] = r1;
      if (tid < 128) sbuf[0][512 + tid] = r2;
    }
    float4 xa = xp[(size_t)(bA * IN_CAPS + i0) * 2];
    float4 xb = xp[(size_t)(bA * IN_CAPS + i0) * 2 + 1];
    __syncthreads();

    for (int ii = 0; ii < I_T; ++ii) {
      const int cur   = ii & 1;
      const bool more = (ii + 1 < I_T);   // uniform
      uint4 p0, p1, p2;
      float4 xan, xbn;
      if (more) {   // issue next-i loads; consumed at bottom -> latency hidden
        const uint4* Whn = Whg + (size_t)(ii + 1) * (NUM_CAPS * 64);
        p0 = Whn[tid];
        p1 = Whn[256 + tid];
        if (tid < 128) p2 = Whn[512 + tid];
        xan = xp[(size_t)(bA * IN_CAPS + (i0 + ii + 1)) * 2];
        xbn = xp[(size_t)(bA * IN_CAPS + (i0 + ii + 1)) * 2 + 1];
      }

      // A-fragment: k0-7 = f16(x) hi, k8-15 = residual lo, k>=16 zero
      uint4 ah, al;
      split2(xa.x, xa.y, ah.x, al.x);
      split2(xa.z, xa.w, ah.y, al.y);
      split2(xb.x, xb.y, ah.z, al.z);
      split2(xb.z, xb.w, ah.w, al.w);
      uint4 as = (g == 0) ? ah : ((g == 1) ? al : z4);
      f16x8 af = __builtin_bit_cast(f16x8, as);

      const uint4* sb = sbuf[cur];
      f32x4 u[NUM_CAPS];
#pragma unroll
      for (int n = 0; n < NUM_CAPS; ++n) {
        f16x8 bf = __builtin_bit_cast(f16x8, sb[n * 64 + l]);   // ds_read_b128
        u[n] = __builtin_amdgcn_mfma_f32_16x16x32_f16(af, bf, zc, 0, 0, 0);
      }

      float e[NUM_CAPS][4];
      float es[4] = {0.f, 0.f, 0.f, 0.f};
#pragma unroll
      for (int n = 0; n < NUM_CAPS; ++n)
#pragma unroll
        for (int r = 0; r < 4; ++r) {
          e[n][r] = __expf(red16(u[n][r] * V[n][r]));
          es[r] += e[n][r];
        }
      float inv[4];
#pragma unroll
      for (int r = 0; r < 4; ++r) inv[r] = 1.f / es[r];
#pragma unroll
      for (int n = 0; n < NUM_CAPS; ++n)
#pragma unroll
        for (int r = 0; r < 4; ++r)
          s[n][r] += (e[n][r] * inv[r]) * u[n][r];

      if (more) {
        uint4* nb = sbuf[cur ^ 1];
        nb[tid] = p0;
        nb[256 + tid] = p1;
        if (tid < 128) nb[512 + tid] = p2;
        xa = xan; xb = xbn;
        __syncthreads();
      }
    }

    // spart[tile][b][n][d]; 16 d-lanes per row-group write 64B contiguous
#pragma unroll
    for (int n = 0; n < NUM_CAPS; ++n)
#pragma unroll
      for (int r = 0; r < 4; ++r)
        spart[((size_t)(tile * B_TOT + bC0 + r) * NUM_CAPS + n) * DIM_CAPS + d]
            = s[n][r];

    gbar(bar, 1 + 2 * p);

    // ---- reduce + squash phase (first 160 blocks carry the 40960 elems) ----
    if (gtid < S_ELEMS) {
      float sv = 0.f;
#pragma unroll 16
      for (int tl = 0; tl < P_TILES; ++tl)
        sv += spart[(size_t)tl * S_ELEMS + gtid];
      float sq = sv * sv;
#pragma unroll
      for (int m = 1; m < 16; m <<= 1) sq += __shfl_xor(sq, m, 16);  // sum over d
      float norm = sqrtf(sq);
      float vv = sv * (sq / (1.f + sq)) / (norm + 1e-8f);
      if (p == 3)      out[gtid]  = vv;
      else if (p == 0) Vbuf[gtid] = vv;
      else             Vbuf[gtid] += vv;
    }
    if (p < 3) gbar(bar, 2 + 2 * p);
  }
}

extern "C" void kernel_launch(void* const* d_in, const int* in_sizes, int n_in,
                              void* d_out, int out_size, void* d_ws, size_t ws_size,
                              hipStream_t stream) {
  const float* x = (const float*)d_in[0];  // [256,1152,8]
  const float* W = (const float*)d_in[1];  // [1,10,1152,16,8]
  float* out   = (float*)d_out;            // [256,10,16]
  int*   bar   = (int*)d_ws;
  float* Vbuf  = (float*)d_ws + BAR_I;
  float* spart = Vbuf + VBUF_F;
  uint4* Wh    = (uint4*)(spart + SPART_F);

  // barrier counters must start at 0 every launch (ws is poisoned between runs)
  (void)hipMemsetAsync(bar, 0, BAR_I * sizeof(int), stream);

  caps_kernel<<<NBLK, NTHR, 0, stream>>>(x, W, bar, Wh, Vbuf, spart, out);
}